// Round 6
// baseline (292.498 us; speedup 1.0000x reference)
//
#include <hip/hip_runtime.h>

typedef __bf16 bf16_t;
typedef __bf16 bf16x4_t __attribute__((ext_vector_type(4)));
typedef __bf16 bf16x8 __attribute__((ext_vector_type(8)));
typedef float f32x4 __attribute__((ext_vector_type(4)));

#define NH 8
#define DH 32
#define QL 256
#define KL 256
#define CIN 64
#define HD 256  // NH*DH

__device__ __forceinline__ bf16_t f2bf(float x) { return (bf16_t)x; }

__device__ __forceinline__ f32x4 mfma16(bf16x8 a, bf16x8 b, f32x4 c) {
    return __builtin_amdgcn_mfma_f32_16x16x32_bf16(a, b, c, 0, 0, 0);
}

__device__ __forceinline__ bf16x8 cvt8(const float* __restrict__ p) {
    const f32x4 lo = *(const f32x4*)p;
    const f32x4 hi = *(const f32x4*)(p + 4);
    bf16x8 r;
#pragma unroll
    for (int j = 0; j < 4; ++j) { r[j] = f2bf(lo[j]); r[4 + j] = f2bf(hi[j]); }
    return r;
}

// ---------------------------------------------------------------------------
// Phase 1: project Q (pre-scaled), K, V into MFMA-fragment-native bf16 ws.
//   Qf/Kf per (s,h): 16 tiles x [lane][8], elem = M[tile*16+l16][quad*8+j]
//   Vf  per (s,h): 16 chunks (cs32*2+nt) x [lane][8],
//                  elem = V[cs32*32+quad*8+j][nt*16+l16]
// grid (128 s, 2 half, 3 which): which 0=Q, 1=K, 2=V.
__launch_bounds__(256, 3)
__global__ void proj3(const float* __restrict__ Xq, const float* __restrict__ Xkv,
                      const float* __restrict__ Wq, const float* __restrict__ Wk,
                      const float* __restrict__ Wv,
                      bf16_t* __restrict__ Qf, bf16_t* __restrict__ Kf,
                      bf16_t* __restrict__ Vf) {
    const int s = blockIdx.x, half = blockIdx.y, which = blockIdx.z;
    const int tid = threadIdx.x, lane = tid & 63, w = tid >> 6;
    const int quad = lane >> 4, l16 = lane & 15;
    const f32x4 vzero = {0.f, 0.f, 0.f, 0.f};

    __shared__ __attribute__((aligned(16))) bf16_t sW[HD][CIN + 8];  // W^T, 36.9 KB
    __shared__ __attribute__((aligned(16))) bf16_t sT[4][32][40];    // 10.2 KB transpose buf

    const float* __restrict__ X = (which == 0) ? Xq : Xkv;
    const float* __restrict__ W = (which == 0) ? Wq : (which == 1 ? Wk : Wv);
    const float scale = (which == 0) ? 0.17677669529663687f : 1.0f;  // 1/sqrt(32)

    // stage W^T: sW[n=hd][k=cin], coalesced float4
#pragma unroll
    for (int it = 0; it < 16; ++it) {
        const int idx = it * 256 + tid;
        const int k = idx >> 6, c4 = (idx & 63) << 2;
        const f32x4 w4 = *(const f32x4*)&W[k * HD + c4];
#pragma unroll
        for (int j = 0; j < 4; ++j) sW[c4 + j][k] = f2bf(w4[j]);
    }
    __syncthreads();

    if (which < 2) {
        bf16_t* __restrict__ Dst = which ? Kf : Qf;
#pragma unroll 1
        for (int t = 0; t < 2; ++t) {
            const int mt = half * 8 + w * 2 + t;  // 16-row tile index (0..15)
            const float* xp = &X[(s * QL + mt * 16 + l16) * CIN + quad * 8];
            const bf16x8 a0 = cvt8(xp);
            const bf16x8 a1 = cvt8(xp + 32);
#pragma unroll 1
            for (int h = 0; h < NH; ++h) {
                // C/D: (row=quad*4+r, d=nth*16+l16) -> sT[row][d] -> frag read
#pragma unroll
                for (int nth = 0; nth < 2; ++nth) {
                    const bf16x8 b0 = *(const bf16x8*)&sW[h * DH + nth * 16 + l16][quad * 8];
                    const bf16x8 b1 = *(const bf16x8*)&sW[h * DH + nth * 16 + l16][32 + quad * 8];
                    f32x4 c = mfma16(a0, b0, vzero);
                    c = mfma16(a1, b1, c);
#pragma unroll
                    for (int r = 0; r < 4; ++r)
                        sT[w][quad * 4 + r][nth * 16 + l16] = f2bf(c[r] * scale);
                }
                // same-wave DS ordering: read sees writes above
                const bf16x8 frag = *(const bf16x8*)&sT[w][l16][quad * 8];
                *(bf16x8*)&Dst[((size_t)(s * NH + h) * 16 + mt) * 512 + lane * 8] = frag;
            }
        }
    } else {
        const int cs32 = half * 4 + w;  // 32-kv chunk (0..7)
        bf16x8 a[2][2];
#pragma unroll
        for (int u = 0; u < 2; ++u) {
            const float* xp = &Xkv[(s * KL + cs32 * 32 + u * 16 + l16) * CIN + quad * 8];
            a[u][0] = cvt8(xp);
            a[u][1] = cvt8(xp + 32);
        }
#pragma unroll 1
        for (int h = 0; h < NH; ++h) {
            // C/D: (kv=u*16+quad*4+r, d=nth*16+l16) -> sT[d][kv] (transposed)
#pragma unroll
            for (int u = 0; u < 2; ++u)
#pragma unroll
                for (int nth = 0; nth < 2; ++nth) {
                    const bf16x8 b0 = *(const bf16x8*)&sW[h * DH + nth * 16 + l16][quad * 8];
                    const bf16x8 b1 = *(const bf16x8*)&sW[h * DH + nth * 16 + l16][32 + quad * 8];
                    f32x4 c = mfma16(a[u][0], b0, vzero);
                    c = mfma16(a[u][1], b1, c);
#pragma unroll
                    for (int r = 0; r < 4; ++r)
                        sT[w][nth * 16 + l16][u * 16 + quad * 4 + r] = f2bf(c[r]);
                }
#pragma unroll
            for (int nt = 0; nt < 2; ++nt) {
                const bf16x8 frag = *(const bf16x8*)&sT[w][nt * 16 + l16][quad * 8];
                *(bf16x8*)&Vf[((size_t)(s * NH + h) * 16 + cs32 * 2 + nt) * 512 + lane * 8] = frag;
            }
        }
    }
}

// ---------------------------------------------------------------------------
// Phase 2: attention. block=(s,h); K/V staged to LDS once (lane-linear,
// conflict-free); Q frags preloaded to regs; bias f32x4 from global (L2-hot);
// Ows aliases Qf (each wave reads its Q tiles before overwriting them).
__launch_bounds__(256, 3)
__global__ void attn2(const float* __restrict__ Mask, const float* __restrict__ Bias,
                      const bf16_t* __restrict__ Qf, const bf16_t* __restrict__ Kf,
                      const bf16_t* __restrict__ Vf, bf16_t* __restrict__ Ows) {
    const int s = blockIdx.x, h = blockIdx.y;
    const int tid = threadIdx.x, lane = tid & 63, w = tid >> 6;
    const int quad = lane >> 4, l16 = lane & 15;
    const f32x4 vzero = {0.f, 0.f, 0.f, 0.f};

    __shared__ __attribute__((aligned(16))) bf16_t sKf[16 * 512];   // 16 KB
    __shared__ __attribute__((aligned(16))) bf16_t sVf[16 * 512];   // 16 KB
    __shared__ __attribute__((aligned(16))) bf16_t sPT[4][16][72];  // 9.2 KB
    __shared__ float sMt[KL];                                       // 1 KB

    const size_t base = (size_t)(s * NH + h) * 8192;

    sMt[tid] = (Mask[s * KL + tid] - 1.0f) * 1.0e9f;
#pragma unroll
    for (int it = 0; it < 4; ++it) {
        const int o = (it * 256 + tid) * 8;
        *(bf16x8*)&sKf[o] = *(const bf16x8*)&Kf[base + o];
        *(bf16x8*)&sVf[o] = *(const bf16x8*)&Vf[base + o];
    }
    bf16x8 qfr[4];
#pragma unroll
    for (int i = 0; i < 4; ++i)
        qfr[i] = *(const bf16x8*)&Qf[base + (size_t)(w * 4 + i) * 512 + lane * 8];
    __syncthreads();

#pragma unroll 1
    for (int i = 0; i < 4; ++i) {
        const int tile = w * 4 + i, q0 = tile * 16;
        // S' = K·Q^T: A=K frag (m=kv), B=Q frag (n=q); C/D row=kv-local, col=q
        f32x4 sv[16];
#pragma unroll
        for (int ct = 0; ct < 16; ++ct) {
            const bf16x8 ak = *(const bf16x8*)&sKf[(ct * 64 + lane) * 8];
            sv[ct] = mfma16(ak, qfr[i], vzero);
        }
        const float* bbase = &Bias[(size_t)(h * QL + q0 + l16) * KL];
#pragma unroll
        for (int ct = 0; ct < 16; ++ct) {
            const f32x4 b4 = *(const f32x4*)&bbase[ct * 16 + quad * 4];
            const f32x4 m4 = *(const f32x4*)&sMt[ct * 16 + quad * 4];
            sv[ct] = sv[ct] + b4 + m4;
        }
        // softmax over kv (per-lane 64 values, then xor 16/32 across quads)
        float mx = -1e30f;
#pragma unroll
        for (int ct = 0; ct < 16; ++ct)
#pragma unroll
            for (int r = 0; r < 4; ++r) mx = fmaxf(mx, sv[ct][r]);
        mx = fmaxf(mx, __shfl_xor(mx, 16, 64));
        mx = fmaxf(mx, __shfl_xor(mx, 32, 64));
        float sum = 0.f;
#pragma unroll
        for (int ct = 0; ct < 16; ++ct)
#pragma unroll
            for (int r = 0; r < 4; ++r) {
                const float e = __expf(sv[ct][r] - mx);
                sv[ct][r] = e;
                sum += e;
            }
        sum += __shfl_xor(sum, 16, 64);
        sum += __shfl_xor(sum, 32, 64);
        const float rs = 1.0f / sum;

        // PV in four 64-kv chunks: normalized P^T -> sPT -> A-frags; V from LDS
        f32x4 o0 = vzero, o1 = vzero;
#pragma unroll
        for (int c = 0; c < 4; ++c) {
#pragma unroll
            for (int cc = 0; cc < 4; ++cc) {
                const int ct = c * 4 + cc;
                bf16x4_t pv;
#pragma unroll
                for (int r = 0; r < 4; ++r) pv[r] = f2bf(sv[ct][r] * rs);
                *(bf16x4_t*)&sPT[w][l16][cc * 16 + quad * 4] = pv;
            }
#pragma unroll
            for (int ks = 0; ks < 2; ++ks) {
                const bf16x8 ap  = *(const bf16x8*)&sPT[w][l16][ks * 32 + quad * 8];
                const bf16x8 bv0 = *(const bf16x8*)&sVf[((c * 2 + ks) * 2 + 0) * 512 + lane * 8];
                const bf16x8 bv1 = *(const bf16x8*)&sVf[((c * 2 + ks) * 2 + 1) * 512 + lane * 8];
                o0 = mfma16(ap, bv0, o0);
                o1 = mfma16(ap, bv1, o1);
            }
        }
        // O tile (q=quad*4+r, d=nt*16+l16) -> Ows[s][h][tile][q][d] (aliases Qf)
        bf16_t* dst = &Ows[base + (size_t)tile * 512];
#pragma unroll
        for (int nt = 0; nt < 2; ++nt) {
            const f32x4 o = nt ? o1 : o0;
#pragma unroll
            for (int r = 0; r < 4; ++r)
                dst[(quad * 4 + r) * DH + nt * 16 + l16] = f2bf(o[r]);
        }
    }
}

// ---------------------------------------------------------------------------
// Phase 3: out[32768,64] = O(bf16, [s][h][tile][q][d]) @ wo[256,64] + bo
__launch_bounds__(256, 4)
__global__ void outproj2(const bf16_t* __restrict__ Ows, const float* __restrict__ Wo,
                         const float* __restrict__ Bo, float* __restrict__ Out) {
    const int tid = threadIdx.x, lane = tid & 63, w = tid >> 6;
    const int quad = lane >> 4, l16 = lane & 15;
    const int R = blockIdx.x * 128;
    const int s = R >> 8;

    __shared__ __attribute__((aligned(16))) bf16_t sWoT[CIN][HD + 8];
    __shared__ float sBo[CIN];

#pragma unroll
    for (int it = 0; it < 16; ++it) {
        const int idx = it * 256 + tid;
        const int kk = idx >> 4, c4 = (idx & 15) << 2;
        const f32x4 w4 = *(const f32x4*)&Wo[kk * CIN + c4];
#pragma unroll
        for (int j = 0; j < 4; ++j) sWoT[c4 + j][kk] = f2bf(w4[j]);
    }
    if (tid < CIN) sBo[tid] = Bo[tid];
    __syncthreads();

    const f32x4 vzero = {0.f, 0.f, 0.f, 0.f};
#pragma unroll 1
    for (int i = 0; i < 2; ++i) {
        const int mr0 = R + w * 32 + i * 16;
        const int tile = (mr0 & 255) >> 4;
        // A-frag: a[ks=h][j] = O[q=mr0+l16][hd=ks*32+quad*8+j], 16B contiguous
        bf16x8 a[8];
#pragma unroll
        for (int ks = 0; ks < 8; ++ks)
            a[ks] = *(const bf16x8*)&Ows[((size_t)(s * NH + ks) * 16 + tile) * 512 +
                                         l16 * DH + quad * 8];
        f32x4 acc[4];
#pragma unroll
        for (int nt = 0; nt < 4; ++nt) acc[nt] = vzero;
#pragma unroll
        for (int ks = 0; ks < 8; ++ks)
#pragma unroll
            for (int nt = 0; nt < 4; ++nt) {
                const bf16x8 b = *(const bf16x8*)&sWoT[nt * 16 + l16][ks * 32 + quad * 8];
                acc[nt] = mfma16(a[ks], b, acc[nt]);
            }
#pragma unroll
        for (int nt = 0; nt < 4; ++nt) {
            const float bo = sBo[nt * 16 + l16];
#pragma unroll
            for (int r = 0; r < 4; ++r)
                Out[(mr0 + quad * 4 + r) * CIN + nt * 16 + l16] = acc[nt][r] + bo;
        }
    }
}

extern "C" void kernel_launch(void* const* d_in, const int* in_sizes, int n_in,
                              void* d_out, int out_size, void* d_ws, size_t ws_size,
                              hipStream_t stream) {
    const float* Xq   = (const float*)d_in[0];
    const float* Xkv  = (const float*)d_in[1];
    const float* Mask = (const float*)d_in[2];
    const float* Bias = (const float*)d_in[3];
    const float* Wq   = (const float*)d_in[4];
    const float* Wk   = (const float*)d_in[5];
    const float* Wv   = (const float*)d_in[6];
    const float* Wo   = (const float*)d_in[7];
    const float* Bo   = (const float*)d_in[8];
    float* Out = (float*)d_out;

    const size_t SEG = 16777216;  // 16 MiB; ws >= 48 MiB proven in round 5
    bf16_t* Qf = (bf16_t*)d_ws;
    bf16_t* Kf = (bf16_t*)((char*)d_ws + SEG);
    bf16_t* Vf = (bf16_t*)((char*)d_ws + 2 * SEG);
    bf16_t* Ows = Qf;  // aliases Qf: per-(s,h,tile) read-before-write within one wave

    proj3<<<dim3(128, 2, 3), 256, 0, stream>>>(Xq, Xkv, Wq, Wk, Wv, Qf, Kf, Vf);
    attn2<<<dim3(128, NH), 256, 0, stream>>>(Mask, Bias, Qf, Kf, Vf, Ows);
    outproj2<<<256, 256, 0, stream>>>(Ows, Wo, Bo, Out);
}

// Round 7
// 173.049 us; speedup vs baseline: 1.6903x; 1.6903x over previous
//
#include <hip/hip_runtime.h>

typedef __bf16 bf16_t;
typedef __bf16 bf16x4_t __attribute__((ext_vector_type(4)));
typedef __bf16 bf16x8 __attribute__((ext_vector_type(8)));
typedef float f32x4 __attribute__((ext_vector_type(4)));

#define NH 8
#define DH 32
#define QL 256
#define KL 256
#define CIN 64
#define HD 256  // NH*DH

__device__ __forceinline__ bf16_t f2bf(float x) { return (bf16_t)x; }

__device__ __forceinline__ f32x4 mfma16(bf16x8 a, bf16x8 b, f32x4 c) {
    return __builtin_amdgcn_mfma_f32_16x16x32_bf16(a, b, c, 0, 0, 0);
}

__device__ __forceinline__ bf16x8 cvt8(const float* __restrict__ p) {
    const f32x4 lo = *(const f32x4*)p;
    const f32x4 hi = *(const f32x4*)(p + 4);
    bf16x8 r;
#pragma unroll
    for (int j = 0; j < 4; ++j) { r[j] = f2bf(lo[j]); r[4 + j] = f2bf(hi[j]); }
    return r;
}

// ---------------------------------------------------------------------------
// Phase 1: project Q (pre-scaled), K, V into MFMA-fragment-native bf16 ws.
//   Qf/Kf per (s,h): 16 tiles x [lane][8], elem = M[tile*16+l16][quad*8+j]
//   Vf  per (s,h): 16 chunks (cs32*2+nt) x [lane][8],
//                  elem = V[cs32*32+quad*8+j][nt*16+l16]
// grid (128 s, 2 half, 3 which): which 0=Q, 1=K, 2=V.
__launch_bounds__(256, 2)
__global__ void proj3(const float* __restrict__ Xq, const float* __restrict__ Xkv,
                      const float* __restrict__ Wq, const float* __restrict__ Wk,
                      const float* __restrict__ Wv,
                      bf16_t* __restrict__ Qf, bf16_t* __restrict__ Kf,
                      bf16_t* __restrict__ Vf) {
    const int s = blockIdx.x, half = blockIdx.y, which = blockIdx.z;
    const int tid = threadIdx.x, lane = tid & 63, w = tid >> 6;
    const int quad = lane >> 4, l16 = lane & 15;
    const f32x4 vzero = {0.f, 0.f, 0.f, 0.f};

    __shared__ __attribute__((aligned(16))) bf16_t sW[HD][CIN + 8];   // W^T, 36.9 KB
    __shared__ __attribute__((aligned(16))) bf16_t sT[2][4][32][40];  // 20.5 KB dbuf transpose

    const float* __restrict__ X = (which == 0) ? Xq : Xkv;
    const float* __restrict__ W = (which == 0) ? Wq : (which == 1 ? Wk : Wv);
    const float scale = (which == 0) ? 0.17677669529663687f : 1.0f;  // 1/sqrt(32)

    // stage W^T: sW[n=hd][k=cin], coalesced float4
#pragma unroll
    for (int it = 0; it < 16; ++it) {
        const int idx = it * 256 + tid;
        const int k = idx >> 6, c4 = (idx & 63) << 2;
        const f32x4 w4 = *(const f32x4*)&W[k * HD + c4];
#pragma unroll
        for (int j = 0; j < 4; ++j) sW[c4 + j][k] = f2bf(w4[j]);
    }
    __syncthreads();

    if (which < 2) {
        bf16_t* __restrict__ Dst = which ? Kf : Qf;
#pragma unroll 1
        for (int t = 0; t < 2; ++t) {
            const int mt = half * 8 + w * 2 + t;  // 16-row tile index (0..15)
            const float* xp = &X[(s * QL + mt * 16 + l16) * CIN + quad * 8];
            const bf16x8 a0 = cvt8(xp);
            const bf16x8 a1 = cvt8(xp + 32);
#pragma unroll 2
            for (int h = 0; h < NH; ++h) {
                // C/D: (row=quad*4+r, d=nth*16+l16) -> sT[row][d] -> frag read
#pragma unroll
                for (int nth = 0; nth < 2; ++nth) {
                    const bf16x8 b0 = *(const bf16x8*)&sW[h * DH + nth * 16 + l16][quad * 8];
                    const bf16x8 b1 = *(const bf16x8*)&sW[h * DH + nth * 16 + l16][32 + quad * 8];
                    f32x4 c = mfma16(a0, b0, vzero);
                    c = mfma16(a1, b1, c);
#pragma unroll
                    for (int r = 0; r < 4; ++r)
                        sT[h & 1][w][quad * 4 + r][nth * 16 + l16] = f2bf(c[r] * scale);
                }
                // same-wave DS ordering: read sees writes above
                const bf16x8 frag = *(const bf16x8*)&sT[h & 1][w][l16][quad * 8];
                *(bf16x8*)&Dst[((size_t)(s * NH + h) * 16 + mt) * 512 + lane * 8] = frag;
            }
        }
    } else {
        const int cs32 = half * 4 + w;  // 32-kv chunk (0..7)
        bf16x8 a[2][2];
#pragma unroll
        for (int u = 0; u < 2; ++u) {
            const float* xp = &Xkv[(s * KL + cs32 * 32 + u * 16 + l16) * CIN + quad * 8];
            a[u][0] = cvt8(xp);
            a[u][1] = cvt8(xp + 32);
        }
#pragma unroll 2
        for (int h = 0; h < NH; ++h) {
            // C/D: (kv=u*16+quad*4+r, d=nth*16+l16) -> sT[d][kv] (transposed)
#pragma unroll
            for (int u = 0; u < 2; ++u)
#pragma unroll
                for (int nth = 0; nth < 2; ++nth) {
                    const bf16x8 b0 = *(const bf16x8*)&sW[h * DH + nth * 16 + l16][quad * 8];
                    const bf16x8 b1 = *(const bf16x8*)&sW[h * DH + nth * 16 + l16][32 + quad * 8];
                    f32x4 c = mfma16(a[u][0], b0, vzero);
                    c = mfma16(a[u][1], b1, c);
#pragma unroll
                    for (int r = 0; r < 4; ++r)
                        sT[h & 1][w][nth * 16 + l16][u * 16 + quad * 4 + r] = f2bf(c[r]);
                }
#pragma unroll
            for (int nt = 0; nt < 2; ++nt) {
                const bf16x8 frag = *(const bf16x8*)&sT[h & 1][w][nt * 16 + l16][quad * 8];
                *(bf16x8*)&Vf[((size_t)(s * NH + h) * 16 + cs32 * 2 + nt) * 512 + lane * 8] = frag;
            }
        }
    }
}

// ---------------------------------------------------------------------------
// Phase 2: attention, barrier-free pure consumer. grid (128 s, 4 qt, 8 h) =
// 4096 blocks (r5's proven L2-friendly shape: s-fastest, h slowest). Each wave
// owns ONE 16-row q-tile; Q/K/V frags are lane-linear 16B loads straight from
// ws (K/V shared in L2 by the 4 qt-blocks of the same (s,h)); bias/mask f32x4
// from global (L2-hot). LDS only for the P^T round-trip. No __syncthreads.
__launch_bounds__(256, 4)
__global__ void attn3(const float* __restrict__ Mask, const float* __restrict__ Bias,
                      const bf16_t* __restrict__ Qf, const bf16_t* __restrict__ Kf,
                      const bf16_t* __restrict__ Vf, bf16_t* __restrict__ Ows) {
    const int s = blockIdx.x, qt = blockIdx.y, h = blockIdx.z;
    const int tid = threadIdx.x, lane = tid & 63, w = tid >> 6;
    const int quad = lane >> 4, l16 = lane & 15;
    const f32x4 vzero = {0.f, 0.f, 0.f, 0.f};

    __shared__ __attribute__((aligned(16))) bf16_t sPT[4][16][72];  // 9.2 KB

    const int tile = qt * 4 + w, q0 = tile * 16;
    const size_t base = (size_t)(s * NH + h) * 8192;

    // Q fragment: one 16B load
    const bf16x8 qfr = *(const bf16x8*)&Qf[base + (size_t)tile * 512 + lane * 8];

    // S' = K·Q^T: A=K frag (m=kv), B=Q frag (n=q); C/D row=kv-local, col=q
    f32x4 sv[16];
#pragma unroll
    for (int ct = 0; ct < 16; ++ct) {
        const bf16x8 ak = *(const bf16x8*)&Kf[base + ct * 512 + lane * 8];
        sv[ct] = mfma16(ak, qfr, vzero);
    }
    // bias (f32x4 along kv) + mask
    const float* bbase = &Bias[(size_t)(h * QL + q0 + l16) * KL];
    const float* mbase = &Mask[s * KL];
#pragma unroll
    for (int ct = 0; ct < 16; ++ct) {
        const f32x4 b4 = *(const f32x4*)&bbase[ct * 16 + quad * 4];
        const f32x4 m4 = *(const f32x4*)&mbase[ct * 16 + quad * 4];
        sv[ct] = sv[ct] + b4 + (m4 - 1.0f) * 1.0e9f;
    }
    // softmax over kv (per-lane 64 values, then xor 16/32 across quads)
    float mx = -1e30f;
#pragma unroll
    for (int ct = 0; ct < 16; ++ct)
#pragma unroll
        for (int r = 0; r < 4; ++r) mx = fmaxf(mx, sv[ct][r]);
    mx = fmaxf(mx, __shfl_xor(mx, 16, 64));
    mx = fmaxf(mx, __shfl_xor(mx, 32, 64));
    float sum = 0.f;
#pragma unroll
    for (int ct = 0; ct < 16; ++ct)
#pragma unroll
        for (int r = 0; r < 4; ++r) {
            const float e = __expf(sv[ct][r] - mx);
            sv[ct][r] = e;
            sum += e;
        }
    sum += __shfl_xor(sum, 16, 64);
    sum += __shfl_xor(sum, 32, 64);
    const float rs = 1.0f / sum;

    // PV in four 64-kv chunks: normalized P^T -> sPT -> A-frags; V from global
    f32x4 o0 = vzero, o1 = vzero;
#pragma unroll
    for (int c = 0; c < 4; ++c) {
#pragma unroll
        for (int cc = 0; cc < 4; ++cc) {
            const int ct = c * 4 + cc;
            bf16x4_t pv;
#pragma unroll
            for (int r = 0; r < 4; ++r) pv[r] = f2bf(sv[ct][r] * rs);
            *(bf16x4_t*)&sPT[w][l16][cc * 16 + quad * 4] = pv;
        }
#pragma unroll
        for (int ks = 0; ks < 2; ++ks) {
            const bf16x8 ap  = *(const bf16x8*)&sPT[w][l16][ks * 32 + quad * 8];
            const bf16x8 bv0 = *(const bf16x8*)&Vf[base + ((c * 2 + ks) * 2 + 0) * 512 + lane * 8];
            const bf16x8 bv1 = *(const bf16x8*)&Vf[base + ((c * 2 + ks) * 2 + 1) * 512 + lane * 8];
            o0 = mfma16(ap, bv0, o0);
            o1 = mfma16(ap, bv1, o1);
        }
    }
    // O tile (q=quad*4+r, d=nt*16+l16) -> Ows[s][h][tile][q][d] (aliases Qf;
    // qfr was consumed before this store -> read-before-write within the wave)
    bf16_t* dst = &Ows[base + (size_t)tile * 512];
#pragma unroll
    for (int nt = 0; nt < 2; ++nt) {
        const f32x4 o = nt ? o1 : o0;
#pragma unroll
        for (int r = 0; r < 4; ++r)
            dst[(quad * 4 + r) * DH + nt * 16 + l16] = f2bf(o[r]);
    }
}

// ---------------------------------------------------------------------------
// Phase 3: out[32768,64] = O(bf16, [s][h][tile][q][d]) @ wo[256,64] + bo
__launch_bounds__(256, 4)
__global__ void outproj2(const bf16_t* __restrict__ Ows, const float* __restrict__ Wo,
                         const float* __restrict__ Bo, float* __restrict__ Out) {
    const int tid = threadIdx.x, lane = tid & 63, w = tid >> 6;
    const int quad = lane >> 4, l16 = lane & 15;
    const int R = blockIdx.x * 128;
    const int s = R >> 8;

    __shared__ __attribute__((aligned(16))) bf16_t sWoT[CIN][HD + 8];
    __shared__ float sBo[CIN];

#pragma unroll
    for (int it = 0; it < 16; ++it) {
        const int idx = it * 256 + tid;
        const int kk = idx >> 4, c4 = (idx & 15) << 2;
        const f32x4 w4 = *(const f32x4*)&Wo[kk * CIN + c4];
#pragma unroll
        for (int j = 0; j < 4; ++j) sWoT[c4 + j][kk] = f2bf(w4[j]);
    }
    if (tid < CIN) sBo[tid] = Bo[tid];
    __syncthreads();

    const f32x4 vzero = {0.f, 0.f, 0.f, 0.f};
#pragma unroll 1
    for (int i = 0; i < 2; ++i) {
        const int mr0 = R + w * 32 + i * 16;
        const int tile = (mr0 & 255) >> 4;
        // A-frag: a[ks=h][j] = O[q=mr0+l16][hd=ks*32+quad*8+j], 16B contiguous
        bf16x8 a[8];
#pragma unroll
        for (int ks = 0; ks < 8; ++ks)
            a[ks] = *(const bf16x8*)&Ows[((size_t)(s * NH + ks) * 16 + tile) * 512 +
                                         l16 * DH + quad * 8];
        f32x4 acc[4];
#pragma unroll
        for (int nt = 0; nt < 4; ++nt) acc[nt] = vzero;
#pragma unroll
        for (int ks = 0; ks < 8; ++ks)
#pragma unroll
            for (int nt = 0; nt < 4; ++nt) {
                const bf16x8 b = *(const bf16x8*)&sWoT[nt * 16 + l16][ks * 32 + quad * 8];
                acc[nt] = mfma16(a[ks], b, acc[nt]);
            }
#pragma unroll
        for (int nt = 0; nt < 4; ++nt) {
            const float bo = sBo[nt * 16 + l16];
#pragma unroll
            for (int r = 0; r < 4; ++r)
                Out[(mr0 + quad * 4 + r) * CIN + nt * 16 + l16] = acc[nt][r] + bo;
        }
    }
}

extern "C" void kernel_launch(void* const* d_in, const int* in_sizes, int n_in,
                              void* d_out, int out_size, void* d_ws, size_t ws_size,
                              hipStream_t stream) {
    const float* Xq   = (const float*)d_in[0];
    const float* Xkv  = (const float*)d_in[1];
    const float* Mask = (const float*)d_in[2];
    const float* Bias = (const float*)d_in[3];
    const float* Wq   = (const float*)d_in[4];
    const float* Wk   = (const float*)d_in[5];
    const float* Wv   = (const float*)d_in[6];
    const float* Wo   = (const float*)d_in[7];
    const float* Bo   = (const float*)d_in[8];
    float* Out = (float*)d_out;

    const size_t SEG = 16777216;  // 16 MiB; ws >= 48 MiB proven in round 5
    bf16_t* Qf = (bf16_t*)d_ws;
    bf16_t* Kf = (bf16_t*)((char*)d_ws + SEG);
    bf16_t* Vf = (bf16_t*)((char*)d_ws + 2 * SEG);
    bf16_t* Ows = Qf;  // aliases Qf: per-(s,h,tile) read-before-write within one wave

    proj3<<<dim3(128, 2, 3), 256, 0, stream>>>(Xq, Xkv, Wq, Wk, Wv, Qf, Kf, Vf);
    attn3<<<dim3(128, 4, NH), 256, 0, stream>>>(Mask, Bias, Qf, Kf, Vf, Ows);
    outproj2<<<256, 256, 0, stream>>>(Ows, Wo, Bo, Out);
}